// Round 4
// baseline (297.660 us; speedup 1.0000x reference)
//
#include <hip/hip_runtime.h>
#include <hip/hip_bf16.h>

// MultiScaleEdgeBuilder: all-pairs mask + 16-wide Gaussian RBF.
// N=2048, NUM_RBF=16, CUTOFF=8.0, NUM_GRAPHS=16.
// Float tensors may be bf16 OR f32; batch int32 or int64 (autodetected).
//
// R11: fill-mimic dense-sweep restructure. Evidence: kernel segment is
// ~100-106us (2.85 TB/s) invariant across R8/R9/R10 (micro-blocks vs
// row-blocks vs nt-vs-plain all null), while rocclr fillBuffer sustains
// 6.3 TB/s with plain stores in the SAME profile. Remaining structural
// difference: fill is a grid-stride sweep (all waves store in a ~1-2 MB
// dense sliding window -> DRAM page locality); ours had 2048 co-resident
// private streams spanning all 285 MB at once (row-buffer thrash).
// New: 512-block grid-stride sweep over 16B chunks (2 MB window), rbf then
// mask; per-row [lo,hi) precomputed into d_ws by a tiny pre-kernel
// (batch sorted => same-graph j's contiguous).

constexpr int N    = 2048;
constexpr int NRBF = 16;
constexpr int NBLK = 512;              // dense-window grid
constexpr int T    = NBLK * 256;       // 131072 threads in flight

typedef float  f32x4  __attribute__((ext_vector_type(4)));
typedef short  s16x8  __attribute__((ext_vector_type(8)));
typedef int    i32x2  __attribute__((ext_vector_type(2)));

__device__ inline float bf16_bits_to_f32(unsigned short h) {
    union { unsigned int u; float f; } c;
    c.u = ((unsigned int)h) << 16;
    return c.f;
}

__device__ inline short f32_to_bf16_bits(float f) {
    __hip_bfloat16 b = __float2bfloat16(f);
    union { __hip_bfloat16 b; short s; } c; c.b = b;
    return c.s;
}

// numpy-exact fp32 distance: no FMA contraction, IEEE sqrt, ref op order.
__device__ inline float pair_dist(float xi, float yi, float zi,
                                  float xj, float yj, float zj) {
    const float dx = __fadd_rn(__fsub_rn(xi, xj), 1e-10f);
    const float dy = __fadd_rn(__fsub_rn(yi, yj), 1e-10f);
    const float dz = __fadd_rn(__fsub_rn(zi, zj), 1e-10f);
    const float d2 = __fadd_rn(__fadd_rn(__fmul_rn(dx, dx), __fmul_rn(dy, dy)),
                               __fmul_rn(dz, dz));
    return __fsqrt_rn(d2);
}

// ---- pre-kernel: per-row contiguous same-graph range [lo,hi) -> ws ----
__global__ __launch_bounds__(256) void row_range_kernel(
    const int* __restrict__ batch32, int* __restrict__ ws)
{
    const int i = blockIdx.x * 256 + threadIdx.x;   // 0..N-1
    // int64 batch: word N-1 is a HIGH word = 0; int32: max graph id != 0.
    const bool b64 = (batch32[N - 1] == 0);
    const int g = b64 ? batch32[2 * i] : batch32[i];
    int l = 0, h = N;
    while (l < h) {                      // lower_bound(g)
        int m  = (l + h) >> 1;
        int bm = b64 ? batch32[2 * m] : batch32[m];
        if (bm < g) l = m + 1; else h = m;
    }
    const int lo = l;
    h = N;
    while (l < h) {                      // upper_bound(g)
        int m  = (l + h) >> 1;
        int bm = b64 ? batch32[2 * m] : batch32[m];
        if (bm <= g) l = m + 1; else h = m;
    }
    ws[2 * i]     = lo;
    ws[2 * i + 1] = l;
}

__global__ __launch_bounds__(256) void edge_rbf_kernel(
    const void* __restrict__ pos_raw,
    const void* __restrict__ centers_raw,
    const void* __restrict__ width_raw,
    const int*  __restrict__ ws,
    void*       __restrict__ out_raw)
{
    const int g0 = blockIdx.x * 256 + threadIdx.x;  // global thread id

    // ---- inline dtype detection (uniform; L1-resident) ----
    const unsigned int* posw = (const unsigned int*)pos_raw;
    int cnt = 0;
#pragma unroll
    for (int k = 0; k < 16; ++k) {
        float v = bf16_bits_to_f32((unsigned short)(posw[k] & 0xFFFFu));
        float a = fabsf(v);
        if (a > 1e-6f && a < 100.0f) ++cnt;
    }
    const bool is_bf16 = (cnt >= 12);

    if (!is_bf16) {
        const float* pos     = (const float*)pos_raw;
        const float* centers = (const float*)centers_raw;
        const float* width   = (const float*)width_raw;
        float* mask_out = (float*)out_raw;
        float* rbf_out  = mask_out + (size_t)N * N;

        const float w = width[0];
        float cen[NRBF];
#pragma unroll
        for (int r = 0; r < NRBF; ++r) cen[r] = centers[r];
        const float ninv = -1.0f / (2.0f * w * w);

        // ---- rbf sweep: 2048*2048*16/4 = 16,777,216 16B chunks, 128 iters --
        for (int k = 0; k < 128; ++k) {
            const int c    = g0 + k * T;
            const int pidx = c >> 2;            // pair index i*N+j
            const int q    = c & 3;             // comp quad
            const int i    = pidx >> 11;
            const int j    = pidx & (N - 1);
            const i32x2 lh = *(const i32x2*)(ws + 2 * i);
            f32x4 o = (f32x4)0.0f;
            if ((j >= lh[0]) & (j < lh[1]) & (j != i)) {
                const float d = pair_dist(pos[3*i], pos[3*i+1], pos[3*i+2],
                                          pos[3*j], pos[3*j+1], pos[3*j+2]);
                if (d < 8.0f) {
#pragma unroll
                    for (int u = 0; u < 4; ++u) {
                        const float tt = d - cen[4 * q + u];
                        o[u] = __expf(tt * tt * ninv);
                    }
                }
            }
            *(f32x4*)(rbf_out + (size_t)c * 4) = o;
        }

        // ---- mask sweep: 2048*2048/4 = 1,048,576 chunks, 8 iters ----
        for (int k = 0; k < 8; ++k) {
            const int c  = g0 + k * T;
            const int i  = c >> 9;              // 512 chunks per row
            const int j0 = (c & 511) * 4;
            const i32x2 lh = *(const i32x2*)(ws + 2 * i);
            const float xi = pos[3*i], yi = pos[3*i+1], zi = pos[3*i+2];
            f32x4 o;
#pragma unroll
            for (int m = 0; m < 4; ++m) {
                const int j = j0 + m;
                float v = 0.0f;
                if ((j >= lh[0]) & (j < lh[1]) & (j != i)) {
                    const float d = pair_dist(xi, yi, zi,
                                              pos[3*j], pos[3*j+1], pos[3*j+2]);
                    v = (d < 8.0f) ? 1.0f : 0.0f;
                }
                o[m] = v;
            }
            *(f32x4*)(mask_out + (size_t)c * 4) = o;
        }
    } else {
        const __hip_bfloat16* pos     = (const __hip_bfloat16*)pos_raw;
        const __hip_bfloat16* centers = (const __hip_bfloat16*)centers_raw;
        const __hip_bfloat16* width   = (const __hip_bfloat16*)width_raw;
        short* mask_out = (short*)out_raw;
        short* rbf_out  = mask_out + (size_t)N * N;

        const float w = __bfloat162float(width[0]);
        float cen[NRBF];
#pragma unroll
        for (int r = 0; r < NRBF; ++r) cen[r] = __bfloat162float(centers[r]);
        const float ninv = -1.0f / (2.0f * w * w);

        // ---- rbf sweep: 2048*2048*16*2/16 = 8,388,608 chunks, 64 iters ----
        for (int k = 0; k < 64; ++k) {
            const int c    = g0 + k * T;
            const int pidx = c >> 1;
            const int h8   = (c & 1) * 8;       // comp octet base
            const int i    = pidx >> 11;
            const int j    = pidx & (N - 1);
            const i32x2 lh = *(const i32x2*)(ws + 2 * i);
            s16x8 o = (s16x8)0;
            if ((j >= lh[0]) & (j < lh[1]) & (j != i)) {
                const float d = pair_dist(
                    __bfloat162float(pos[3*i]),   __bfloat162float(pos[3*i+1]),
                    __bfloat162float(pos[3*i+2]),
                    __bfloat162float(pos[3*j]),   __bfloat162float(pos[3*j+1]),
                    __bfloat162float(pos[3*j+2]));
                if (d < 8.0f) {
#pragma unroll
                    for (int u = 0; u < 8; ++u) {
                        const float tt = d - cen[h8 + u];
                        o[u] = f32_to_bf16_bits(__expf(tt * tt * ninv));
                    }
                }
            }
            *(s16x8*)(rbf_out + (size_t)c * 8) = o;
        }

        // ---- mask sweep: 2048*2048*2/16 = 524,288 chunks, 4 iters ----
        for (int k = 0; k < 4; ++k) {
            const int c  = g0 + k * T;
            const int i  = c >> 8;              // 256 chunks per row
            const int j0 = (c & 255) * 8;
            const i32x2 lh = *(const i32x2*)(ws + 2 * i);
            const float xi = __bfloat162float(pos[3*i]);
            const float yi = __bfloat162float(pos[3*i+1]);
            const float zi = __bfloat162float(pos[3*i+2]);
            s16x8 o;
#pragma unroll
            for (int m = 0; m < 8; ++m) {
                const int j = j0 + m;
                float v = 0.0f;
                if ((j >= lh[0]) & (j < lh[1]) & (j != i)) {
                    const float d = pair_dist(
                        xi, yi, zi,
                        __bfloat162float(pos[3*j]), __bfloat162float(pos[3*j+1]),
                        __bfloat162float(pos[3*j+2]));
                    v = (d < 8.0f) ? 1.0f : 0.0f;
                }
                o[m] = f32_to_bf16_bits(v);
            }
            *(s16x8*)(mask_out + (size_t)c * 8) = o;
        }
    }
}

extern "C" void kernel_launch(void* const* d_in, const int* in_sizes, int n_in,
                              void* d_out, int out_size, void* d_ws, size_t ws_size,
                              hipStream_t stream) {
    const void* pos     = d_in[0];
    const int*  batch   = (const int*)d_in[1];
    const void* centers = d_in[2];
    const void* width   = d_in[3];

    // pre-pass: per-row [lo,hi) table (16 KB) into workspace
    row_range_kernel<<<dim3(N / 256), dim3(256), 0, stream>>>(
        batch, (int*)d_ws);

    edge_rbf_kernel<<<dim3(NBLK), dim3(256), 0, stream>>>(
        pos, centers, width, (const int*)d_ws, d_out);
}